// Round 1
// baseline (302.409 us; speedup 1.0000x reference)
//
#include <hip/hip_runtime.h>

// Register-resident fused-8 Jacobi, v4: 512-thread retile (4x2 patches).
//  - v3 (256 thr, 4x4 patches) had 80 persistent floats + 32-reg f-staging peak
//    -> unified-file pressure ~190/wave: 84 arch VGPR + AGPR + ~11-dword scratch
//    (WRITE_SIZE 73.8MB vs 33.5 logical), occupancy capped at 2 blocks/CU (25%).
//  - v4: thread = 4-wide x 2-tall patch; persistent state 40 floats
//    (u8 + wN/wS/wW/Fc 32); f staged as ONE aligned float4/row, 4th value
//    (col+4) pulled from lane+1 via DPP (garbage at tile col 63 is discard-halo
//    tight: spreads to col 56 by step 8; output ends at col 55).
//  - W/E halo via DPP wave_shr1/shl1; N/S via dbuf LDS rows (tid +- 16).
//  - kappa via global_load_lds DMA; LDS 32KB/block (exchange dbuf overlays kT).

namespace {
constexpr int    G    = 1024, Ni = 1022;
constexpr int    TOUT = 48, HALO = 8;
constexpr int    KSTR = 68;                       // kT row stride (floats)
constexpr size_t IMG_K = (size_t)G * G;
constexpr size_t IMG_P = (size_t)Ni * Ni;
constexpr size_t WSTR  = 1024;
constexpr size_t IMG_W = (size_t)1024 * 1024;
constexpr float  H2 = (float)(1.0 / (1023.0 * 1023.0));
// LDS: kT[66*68]=4488 floats (17,952B) overlaid by dbuf exchange 2*4096 floats.
}

__device__ __forceinline__ float frcp(float x) { return __builtin_amdgcn_rcpf(x); }

__device__ __forceinline__ void dma16(const float* g, float* l) {
    __builtin_amdgcn_global_load_lds(
        (const __attribute__((address_space(1))) void*)g,
        (__attribute__((address_space(3))) void*)l, 16, 0, 0);
}

// lane l <- lane l-1 (wave_shr1); shifted-in lane gets 0 (bound_ctrl)
__device__ __forceinline__ float lane_shr1(float x) {
    return __builtin_bit_cast(float,
        __builtin_amdgcn_update_dpp(0, __builtin_bit_cast(int, x), 0x138, 0xF, 0xF, true));
}
// lane l <- lane l+1 (wave_shl1)
__device__ __forceinline__ float lane_shl1(float x) {
    return __builtin_bit_cast(float,
        __builtin_amdgcn_update_dpp(0, __builtin_bit_cast(int, x), 0x130, 0xF, 0xF, true));
}

template<bool FIRST, bool LAST>
__global__ __launch_bounds__(512, 2)
void jac_fused8(const float* __restrict__ usrc, float* __restrict__ udst,
                const float* __restrict__ kap,  const float* __restrict__ fin)
{
    __shared__ __align__(16) float lds[8192];
    float* kT = lds;                               // 66 rows x 68 stride (staging phase)

    const int tid = threadIdx.x;
    const int pr = tid >> 4, pc = tid & 15;        // 32 x 16 threads
    const int R0 = pr * 2, C0 = pc * 4;            // 2-tall x 4-wide patch
    const int bx = blockIdx.x, by = blockIdx.y, b = blockIdx.z;
    const int X0 = bx * TOUT - HALO, Y0 = by * TOUT - HALO;

    const float* kB = kap + (size_t)b * IMG_K;
    const float* fB = fin + (size_t)b * IMG_K;
    const bool fast = (bx >= 1) && (bx <= 20) && (by >= 1) && (by <= 20);

    // ---- kappa staging (issue DMA first so it's in flight) ----
    if (fast) {
        const float* gk = kB + (size_t)Y0 * G + X0;   // rows Y0..Y0+65 all in-bounds
        #pragma unroll
        for (int it = 0; it < 3; ++it) {
            const int idx = it * 512 + tid;           // chunk id, 1122 total (17/row)
            if (it < 2 || idx < 1122) {
                const int r = idx / 17, c4 = idx - r * 17;
                dma16(gk + (size_t)r * G + c4 * 4,
                      kT + (size_t)(it * 512 + (tid & 448)) * 4);
            }
        }
    } else {
        for (int lin = tid; lin < 66 * 68; lin += 512) {
            const int r = lin / 68, c = lin - r * 68;
            const int gy = Y0 + r, gx = X0 + c;
            float v = 0.0f;
            if ((unsigned)gy < (unsigned)G && (unsigned)gx < (unsigned)G)
                v = kB[(size_t)gy * G + gx];
            kT[lin] = v;
        }
    }

    // ---- u patch into registers ----
    float u[2][4];
    if (FIRST) {
        const float* uS = usrc + (size_t)b * IMG_P;   // pre, stride 1022
        if (fast) {                                   // all in-bounds; rows 8B-aligned
            #pragma unroll
            for (int dr = 0; dr < 2; ++dr) {
                const float* p = uS + (size_t)(Y0 + R0 + dr) * Ni + (X0 + C0);
                const float2 a = *(const float2*)p;
                const float2 c2 = *(const float2*)(p + 2);
                u[dr][0] = a.x; u[dr][1] = a.y; u[dr][2] = c2.x; u[dr][3] = c2.y;
            }
        } else {
            #pragma unroll
            for (int dr = 0; dr < 2; ++dr) {
                const int gy = Y0 + R0 + dr;
                #pragma unroll
                for (int dc = 0; dc < 4; ++dc) {
                    const int gx = X0 + C0 + dc;
                    u[dr][dc] = ((unsigned)gy < (unsigned)Ni && (unsigned)gx < (unsigned)Ni)
                              ? uS[(size_t)gy * Ni + gx] : 0.0f;
                }
            }
        }
    } else {
        const float* uS = usrc + (size_t)b * IMG_W;   // ws, stride 1024, zero-padded
        const int gx = X0 + C0;
        #pragma unroll
        for (int dr = 0; dr < 2; ++dr) {
            const int gy = Y0 + R0 + dr;
            float4 v = make_float4(0.f, 0.f, 0.f, 0.f);
            if ((unsigned)gy < 1024u && (unsigned)gx <= 1020u)
                v = *(const float4*)(uS + (size_t)gy * WSTR + gx);
            u[dr][0] = v.x; u[dr][1] = v.y; u[dr][2] = v.z; u[dr][3] = v.w;
        }
    }

    // ---- f direct to registers: ONE aligned float4 per row; 4th needed value
    //      (grid col X0+C0+4) comes from lane+1 via DPP after the loads. ----
    float4 fq[2];
    {
        const int fx0 = X0 + C0;
        #pragma unroll
        for (int dr = 0; dr < 2; ++dr) {
            const int gy = Y0 + 1 + R0 + dr;
            if (fast) {
                fq[dr] = *(const float4*)(fB + (size_t)gy * G + fx0);
            } else {
                fq[dr] = make_float4(0.f, 0.f, 0.f, 0.f);
                if ((unsigned)gy < (unsigned)G && (unsigned)fx0 <= (unsigned)(G - 4))
                    fq[dr] = *(const float4*)(fB + (size_t)gy * G + fx0);
            }
        }
    }
    __syncthreads();   // drains kappa DMA + register loads before kT reads

    // ---- iteration-invariant weights; wE implicit (== 1 - wN - wS - wW) ----
    float wN[2][4], wS[2][4], wW[2][4], Fc[2][4];
    float rm[2], cm[4];                                // boundary masks (0/1)
    {
        float ka[6], kb2[6], kc2[6];
        auto loadK = [&](int r, float* dst) {
            const float4 q = *(const float4*)(kT + r * KSTR + C0);
            const float2 p = *(const float2*)(kT + r * KSTR + C0 + 4);
            dst[0] = q.x; dst[1] = q.y; dst[2] = q.z; dst[3] = q.w; dst[4] = p.x; dst[5] = p.y;
        };
        loadK(R0 + 0, ka);
        loadK(R0 + 1, kb2);
        #pragma unroll
        for (int dr = 0; dr < 2; ++dr) {
            loadK(R0 + dr + 2, kc2);
            const float fE = lane_shl1(fq[dr].x);      // lane+1's col (pc=15: halo-safe garbage)
            const float frow[4] = {fq[dr].y, fq[dr].z, fq[dr].w, fE};
            const int gy = Y0 + R0 + dr;
            rm[dr] = ((unsigned)gy < (unsigned)Ni) ? 1.0f : 0.0f;
            #pragma unroll
            for (int dc = 0; dc < 4; ++dc) {
                const float kn = ka[dc + 1], kc = kb2[dc + 1], kw = kb2[dc],
                            ke = kb2[dc + 2], ks = kc2[dc + 1];
                const float y3  = 2.0f * kc + 0.5f * (kn + ks + kw + ke);
                const float inv = frcp(y3);
                const int gx = X0 + C0 + dc;
                const bool dv = ((unsigned)gy < (unsigned)Ni) && ((unsigned)gx < (unsigned)Ni);
                if (dr == 0) cm[dc] = ((unsigned)gx < (unsigned)Ni) ? 1.0f : 0.0f;
                wN[dr][dc] = dv ? 0.5f * (kc + kn) * inv : 0.0f;
                wS[dr][dc] = dv ? 0.5f * (kc + ks) * inv : 0.0f;
                wW[dr][dc] = dv ? 0.5f * (kc + kw) * inv : 0.0f;
                Fc[dr][dc] = dv ? frow[dc] * H2 * inv : 0.0f;
            }
            #pragma unroll
            for (int i = 0; i < 6; ++i) { ka[i] = kb2[i]; kb2[i] = kc2[i]; }
        }
    }
    __syncthreads();   // kT dead; exchange dbuf overlays it

    // ---- 8 steps; N/S via dbuf LDS rows, W/E via DPP lane+-1 ----
    const int tN = (tid >= 16)  ? tid - 16 : 0;
    const int tS = (tid < 496)  ? tid + 16 : 511;

    auto run = [&](bool masked) {
        #pragma unroll
        for (int t = 1; t <= 8; ++t) {
            float* ex   = lds + ((t & 1) ? 0 : 4096);
            float* rowT = ex; float* rowB = ex + 2048;
            *(float4*)(rowT + tid * 4) = make_float4(u[0][0], u[0][1], u[0][2], u[0][3]);
            *(float4*)(rowB + tid * 4) = make_float4(u[1][0], u[1][1], u[1][2], u[1][3]);
            __syncthreads();
            const float4 hN = *(const float4*)(rowB + tN * 4);
            const float4 hS = *(const float4*)(rowT + tS * 4);
            float pn0 = hN.x, pn1 = hN.y, pn2 = hN.z, pn3 = hN.w;
            #pragma unroll
            for (int dr = 0; dr < 2; ++dr) {
                const float uWh = lane_shr1(u[dr][3]);   // old col3 of lane-1
                const float uEh = lane_shl1(u[dr][0]);   // old col0 of lane+1
                float s0, s1, s2, s3;
                if (dr < 1) { s0 = u[1][0]; s1 = u[1][1]; s2 = u[1][2]; s3 = u[1][3]; }
                else        { s0 = hS.x;    s1 = hS.y;    s2 = hS.z;    s3 = hS.w;    }
                const float o0 = u[dr][0], o1 = u[dr][1], o2 = u[dr][2], o3 = u[dr][3];
                // u' = (Fc + uE) + wN*(uN-uE) + wS*(uS-uE) + wW*(uW-uE)
                float v0 = fmaf(wW[dr][0], uWh - o1,
                           fmaf(wS[dr][0], s0  - o1,
                           fmaf(wN[dr][0], pn0 - o1, Fc[dr][0] + o1)));
                float v1 = fmaf(wW[dr][1], o0  - o2,
                           fmaf(wS[dr][1], s1  - o2,
                           fmaf(wN[dr][1], pn1 - o2, Fc[dr][1] + o2)));
                float v2 = fmaf(wW[dr][2], o1  - o3,
                           fmaf(wS[dr][2], s2  - o3,
                           fmaf(wN[dr][2], pn2 - o3, Fc[dr][2] + o3)));
                float v3 = fmaf(wW[dr][3], o2  - uEh,
                           fmaf(wS[dr][3], s3  - uEh,
                           fmaf(wN[dr][3], pn3 - uEh, Fc[dr][3] + uEh)));
                if (masked) {   // out-of-domain points must stay 0 (implicit wE=1 would leak uE)
                    const float r = rm[dr];
                    v0 *= r * cm[0]; v1 *= r * cm[1]; v2 *= r * cm[2]; v3 *= r * cm[3];
                }
                u[dr][0] = v0; u[dr][1] = v1; u[dr][2] = v2; u[dr][3] = v3;
                pn0 = o0; pn1 = o1; pn2 = o2; pn3 = o3;
            }
        }
    };
    if (fast) run(false); else run(true);   // block-uniform branch

    // ---- store valid region [8,56)^2 (pr 4..27, pc 2..13) ----
    if (pr >= 4 && pr < 28 && pc >= 2 && pc < 14) {
        const int gx = X0 + C0;                       // multiple of 4, >= 0
        if (LAST) {
            float* oB = udst + (size_t)b * IMG_P;     // stride 1022
            #pragma unroll
            for (int dr = 0; dr < 2; ++dr) {
                const int gy = Y0 + R0 + dr;
                if (gy < Ni) {
                    float* p = oB + (size_t)gy * Ni + gx;
                    if (gx + 1 < Ni) *(float2*)(p)     = make_float2(u[dr][0], u[dr][1]);
                    if (gx + 3 < Ni) *(float2*)(p + 2) = make_float2(u[dr][2], u[dr][3]);
                }
            }
        } else {
            float* oB = udst + (size_t)b * IMG_W;     // stride 1024, zero pads intact
            #pragma unroll
            for (int dr = 0; dr < 2; ++dr) {
                const int gy = Y0 + R0 + dr;
                if (gy < 1024 && gx <= 1020)
                    *(float4*)(oB + (size_t)gy * WSTR + gx)
                        = make_float4(u[dr][0], u[dr][1], u[dr][2], u[dr][3]);
            }
        }
    }
}

extern "C" void kernel_launch(void* const* d_in, const int* in_sizes, int n_in,
                              void* d_out, int out_size, void* d_ws, size_t ws_size,
                              hipStream_t stream)
{
    const float* pre = (const float*)d_in[0];
    const float* f   = (const float*)d_in[1];
    const float* kap = (const float*)d_in[2];
    float* out = (float*)d_out;
    float* ws  = (float*)d_ws;                 // needs 8*1024*1024*4 = 33.6 MB

    dim3 blk(512, 1, 1);
    dim3 grd((Ni + TOUT - 1) / TOUT, (Ni + TOUT - 1) / TOUT, 8);   // 22 x 22 x 8

    jac_fused8<true,  false><<<grd, blk, 0, stream>>>(pre, ws,  kap, f);
    jac_fused8<false, true ><<<grd, blk, 0, stream>>>(ws,  out, kap, f);
}

// Round 2
// 196.057 us; speedup vs baseline: 1.5425x; 1.5425x over previous
//
#include <hip/hip_runtime.h>

// Register-resident fused-8 Jacobi, v5: column-per-lane / strip-per-wave.
//  - tile 64x64 (48x48 output, halo 8); block = 512 thr = 8 waves.
//  - lane = one column (64 lanes = 64 cols): W/E halo via DPP lane+-1 (free,
//    edge-lane garbage is discard-halo tight: reaches col 8/55 only at step 9).
//  - wave = 8-row strip; each lane holds its column's 8 rows in registers:
//    N/S neighbors are REGISTER accesses. Only the strip boundary rows
//    (u[0], u[7]) cross waves: 2x ds_write_b32 + 2x ds_read_b32 per lane per
//    step, lane-linear (conflict-free), double-buffered, ONE barrier/step.
//    Halo reads are used only by rows 0/7 -> latency hides under rows 1..6.
//  - explicit wE (no wN+wS+wW+wE==1 contraction): invalid points get all-zero
//    weights -> u'=0 naturally, no masks, no dual code path; update is
//    4 fma + 2 DPP per point.
//  - kappa/f/u loaded straight to registers, row-coalesced (64 consecutive
//    floats per wave-load). No kT LDS tile, no DMA, no staging barrier.
//  - LDS = 2 x 1024 floats (8KB). State/lane = 48 floats persistent.

namespace {
constexpr int    G    = 1024, Ni = 1022;
constexpr int    TOUT = 48;
constexpr size_t IMG_K = (size_t)G * G;
constexpr size_t IMG_P = (size_t)Ni * Ni;
constexpr size_t WSTR  = 1024;
constexpr size_t IMG_W = (size_t)1024 * 1024;
constexpr float  H2 = (float)(1.0 / (1023.0 * 1023.0));
}

__device__ __forceinline__ float frcp(float x) { return __builtin_amdgcn_rcpf(x); }

// lane l <- lane l-1 (wave_shr1); shifted-in lane gets 0 (bound_ctrl)
__device__ __forceinline__ float lane_shr1(float x) {
    return __builtin_bit_cast(float,
        __builtin_amdgcn_update_dpp(0, __builtin_bit_cast(int, x), 0x138, 0xF, 0xF, true));
}
// lane l <- lane l+1 (wave_shl1)
__device__ __forceinline__ float lane_shl1(float x) {
    return __builtin_bit_cast(float,
        __builtin_amdgcn_update_dpp(0, __builtin_bit_cast(int, x), 0x130, 0xF, 0xF, true));
}

template<bool FIRST, bool LAST>
__global__ __launch_bounds__(512, 4)
void jac_fused8(const float* __restrict__ usrc, float* __restrict__ udst,
                const float* __restrict__ kap,  const float* __restrict__ fin)
{
    __shared__ __align__(16) float ex[2048];      // 2 bufs x (top[512] | bot[512])

    const int tid = threadIdx.x;
    const int w   = tid >> 6, l = tid & 63;       // wave id, lane id
    const int bx = blockIdx.x, by = blockIdx.y, b = blockIdx.z;
    const int X0 = bx * TOUT - 8, Y0 = by * TOUT - 8;
    const int gx  = X0 + l;                       // this lane's column
    const int gy0 = Y0 + 8 * w;                   // wave's first row

    const float* kB = kap + (size_t)b * IMG_K;
    const float* fB = fin + (size_t)b * IMG_K;
    const bool fast = (bx >= 1) && (bx <= 20) && (by >= 1) && (by <= 20);

    // ---- stage kappa (10 rows), f (8 rows), u (8 rows) straight to regs ----
    float ka[10], fv[8], u[8];
    if (fast) {                                   // every access in-bounds
        const float* kp = kB + (size_t)gy0 * G + (gx + 1);
        #pragma unroll
        for (int i = 0; i < 10; ++i) ka[i] = kp[(size_t)i * G];
        const float* fp = fB + (size_t)(gy0 + 1) * G + (gx + 1);
        #pragma unroll
        for (int r = 0; r < 8; ++r) fv[r] = fp[(size_t)r * G];
        if (FIRST) {
            const float* uS = usrc + (size_t)b * IMG_P + (size_t)gy0 * Ni + gx;
            #pragma unroll
            for (int r = 0; r < 8; ++r) u[r] = uS[(size_t)r * Ni];
        } else {
            const float* uS = usrc + (size_t)b * IMG_W + (size_t)gy0 * WSTR + gx;
            #pragma unroll
            for (int r = 0; r < 8; ++r) u[r] = uS[(size_t)r * WSTR];
        }
    } else {
        const int cx = gx + 1;
        #pragma unroll
        for (int i = 0; i < 10; ++i) {
            const int ry = gy0 + i;
            ka[i] = ((unsigned)ry < (unsigned)G && (unsigned)cx < (unsigned)G)
                  ? kB[(size_t)ry * G + cx] : 0.0f;
        }
        #pragma unroll
        for (int r = 0; r < 8; ++r) {
            const int ry = gy0 + 1 + r;
            fv[r] = ((unsigned)ry < (unsigned)G && (unsigned)cx < (unsigned)G)
                  ? fB[(size_t)ry * G + cx] : 0.0f;
        }
        if (FIRST) {
            const float* uS = usrc + (size_t)b * IMG_P;
            #pragma unroll
            for (int r = 0; r < 8; ++r) {
                const int gy = gy0 + r;
                u[r] = ((unsigned)gy < (unsigned)Ni && (unsigned)gx < (unsigned)Ni)
                     ? uS[(size_t)gy * Ni + gx] : 0.0f;
            }
        } else {
            const float* uS = usrc + (size_t)b * IMG_W;
            #pragma unroll
            for (int r = 0; r < 8; ++r) {
                const int gy = gy0 + r;
                u[r] = ((unsigned)gy < 1024u && (unsigned)gx < 1024u)
                     ? uS[(size_t)gy * WSTR + gx] : 0.0f;
            }
        }
    }

    // ---- iteration-invariant weights; explicit wE, no masks ----
    float wN[8], wS[8], wW[8], wE[8], Fc[8];
    if (fast) {
        #pragma unroll
        for (int r = 0; r < 8; ++r) {
            const float kn = ka[r], kc = ka[r + 1], ks = ka[r + 2];
            const float kw = lane_shr1(kc), ke = lane_shl1(kc);   // edge lanes: halo-safe garbage
            const float inv = frcp(2.0f * kc + 0.5f * (kn + ks + kw + ke));
            wN[r] = 0.5f * (kc + kn) * inv;
            wS[r] = 0.5f * (kc + ks) * inv;
            wW[r] = 0.5f * (kc + kw) * inv;
            wE[r] = 0.5f * (kc + ke) * inv;
            Fc[r] = fv[r] * H2 * inv;
        }
    } else {
        #pragma unroll
        for (int r = 0; r < 8; ++r) {
            const float kn = ka[r], kc = ka[r + 1], ks = ka[r + 2];
            const float kw = lane_shr1(kc), ke = lane_shl1(kc);
            const float inv = frcp(2.0f * kc + 0.5f * (kn + ks + kw + ke));
            const int gy = gy0 + r;
            const bool dv = ((unsigned)gy < (unsigned)Ni) && ((unsigned)gx < (unsigned)Ni);
            wN[r] = dv ? 0.5f * (kc + kn) * inv : 0.0f;
            wS[r] = dv ? 0.5f * (kc + ks) * inv : 0.0f;
            wW[r] = dv ? 0.5f * (kc + kw) * inv : 0.0f;
            wE[r] = dv ? 0.5f * (kc + ke) * inv : 0.0f;
            Fc[r] = dv ? fv[r] * H2 * inv : 0.0f;
        }
    }

    // ---- 8 steps; N/S in registers, W/E via DPP, boundary rows via LDS ----
    const int iN = (w > 0) ? (512 + tid - 64) : (512 + tid);   // wave w-1's bottom
    const int iS = (w < 7) ? (tid + 64)       : tid;           // wave w+1's top
    #pragma unroll
    for (int t = 0; t < 8; ++t) {
        float* exb = ex + ((t & 1) << 10);
        exb[tid]       = u[0];
        exb[512 + tid] = u[7];
        __syncthreads();
        const float hN = exb[iN];
        const float hS = exb[iS];
        const float o0 = u[0], o1 = u[1], o6 = u[6], o7 = u[7];
        // inner rows 1..6: pure registers (halo-read latency hides under these)
        float prev = o0;
        #pragma unroll
        for (int r = 1; r < 7; ++r) {
            const float cur = u[r], nxt = u[r + 1];
            const float uW = lane_shr1(cur), uE = lane_shl1(cur);
            u[r] = fmaf(wN[r], prev,
                   fmaf(wS[r], nxt,
                   fmaf(wW[r], uW,
                   fmaf(wE[r], uE, Fc[r]))));
            prev = cur;
        }
        {   // row 0 (needs hN; S neighbor is old u[1])
            const float uW = lane_shr1(o0), uE = lane_shl1(o0);
            u[0] = fmaf(wN[0], hN,
                   fmaf(wS[0], o1,
                   fmaf(wW[0], uW,
                   fmaf(wE[0], uE, Fc[0]))));
        }
        {   // row 7 (needs hS; N neighbor is old u[6])
            const float uW = lane_shr1(o7), uE = lane_shl1(o7);
            u[7] = fmaf(wN[7], o6,
                   fmaf(wS[7], hS,
                   fmaf(wW[7], uW,
                   fmaf(wE[7], uE, Fc[7]))));
        }
    }

    // ---- store valid region: waves 1..6 (tile rows 8..55), lanes 8..55 ----
    if (w >= 1 && w <= 6 && l >= 8 && l < 56) {
        if (LAST) {
            float* oB = udst + (size_t)b * IMG_P;
            #pragma unroll
            for (int r = 0; r < 8; ++r) {
                const int gy = gy0 + r;
                if ((unsigned)gy < (unsigned)Ni && (unsigned)gx < (unsigned)Ni)
                    oB[(size_t)gy * Ni + gx] = u[r];
            }
        } else {
            float* oB = udst + (size_t)b * IMG_W;
            #pragma unroll
            for (int r = 0; r < 8; ++r) {
                const int gy = gy0 + r;
                if ((unsigned)gy < 1024u && (unsigned)gx < 1024u)
                    oB[(size_t)gy * WSTR + gx] = u[r];
            }
        }
    }
}

extern "C" void kernel_launch(void* const* d_in, const int* in_sizes, int n_in,
                              void* d_out, int out_size, void* d_ws, size_t ws_size,
                              hipStream_t stream)
{
    const float* pre = (const float*)d_in[0];
    const float* f   = (const float*)d_in[1];
    const float* kap = (const float*)d_in[2];
    float* out = (float*)d_out;
    float* ws  = (float*)d_ws;                 // needs 8*1024*1024*4 = 33.6 MB

    dim3 blk(512, 1, 1);
    dim3 grd((Ni + TOUT - 1) / TOUT, (Ni + TOUT - 1) / TOUT, 8);   // 22 x 22 x 8

    jac_fused8<true,  false><<<grd, blk, 0, stream>>>(pre, ws,  kap, f);
    jac_fused8<false, true ><<<grd, blk, 0, stream>>>(ws,  out, kap, f);
}